// Round 20
// baseline (209.136 us; speedup 1.0000x reference)
//
#include <hip/hip_runtime.h>

#define S_LEN 2048
#define DIM   1024
#define NH    16
#define HD    64

typedef __bf16 bf16x8 __attribute__((ext_vector_type(8)));
typedef __bf16 bf16x4 __attribute__((ext_vector_type(4)));
typedef float  f32x4  __attribute__((ext_vector_type(4)));
typedef float  f32x16 __attribute__((ext_vector_type(16)));
typedef unsigned int u32x4 __attribute__((ext_vector_type(4)));

// softmax scale 1/8 with log2(e) folded in -> use v_exp_f32 (exp2) directly
#define SCALE_Q (0.125f * 1.44269504088896f)

#define GLOAD_LDS16(g, l) __builtin_amdgcn_global_load_lds( \
    (const __attribute__((address_space(1))) void*)(g),     \
    (__attribute__((address_space(3))) void*)(l), 16, 0, 0)

static __device__ __forceinline__ unsigned cvt_pk_bf16(float a, float b) {
  unsigned r;
  asm("v_cvt_pk_bf16_f32 %0, %1, %2" : "=v"(r) : "v"(a), "v"(b));
  return r;   // low16 = bf16(a), high16 = bf16(b)
}

// ---------------- cast x (fp32 -> bf16), 8 elems/thread ----------------
__global__ __launch_bounds__(256) void cast_x_kernel(const float* __restrict__ x,
                                                     __bf16* __restrict__ xb) {
  int i = blockIdx.x * 256 + threadIdx.x;   // 0..524287
  const float4 a = ((const float4*)x)[i * 2];
  const float4 b = ((const float4*)x)[i * 2 + 1];
  bf16x8 o;
  o[0] = (__bf16)a.x; o[1] = (__bf16)a.y; o[2] = (__bf16)a.z; o[3] = (__bf16)a.w;
  o[4] = (__bf16)b.x; o[5] = (__bf16)b.y; o[6] = (__bf16)b.z; o[7] = (__bf16)b.w;
  ((bf16x8*)xb)[i] = o;
}

// ---------------- W [k][n] fp32 -> WT [n][k] bf16, 64x64 LDS tiles ----------------
__global__ __launch_bounds__(256) void transW_kernel(const float* __restrict__ Wq,
                                                     const float* __restrict__ Wk,
                                                     const float* __restrict__ Wv,
                                                     __bf16* __restrict__ WT) {
  int which = blockIdx.z;
  const float* W = (which == 0) ? Wq : ((which == 1) ? Wk : Wv);
  __bf16* o = WT + (size_t)which * DIM * DIM;
  __shared__ __bf16 t[64][65];
  int k0 = blockIdx.y * 64, n0 = blockIdx.x * 64;
  int tid = threadIdx.x;
  int c4 = (tid & 15) * 4, rb = tid >> 4;   // rb 0..15
#pragma unroll
  for (int p = 0; p < 4; ++p) {
    int r = p * 16 + rb;
    float4 a = *(const float4*)&W[(size_t)(k0 + r) * DIM + n0 + c4];
    t[r][c4 + 0] = (__bf16)a.x; t[r][c4 + 1] = (__bf16)a.y;
    t[r][c4 + 2] = (__bf16)a.z; t[r][c4 + 3] = (__bf16)a.w;
  }
  __syncthreads();
#pragma unroll
  for (int p = 0; p < 4; ++p) {
    int n = p * 16 + rb;                     // output row (n dim)
    bf16x4 v;
    v[0] = t[c4 + 0][n]; v[1] = t[c4 + 1][n];
    v[2] = t[c4 + 2][n]; v[3] = t[c4 + 3][n];
    *(bf16x4*)&o[(size_t)(n0 + n) * DIM + k0 + c4] = v;
  }
}

// ---------------- QKV GEMM, m97 structure + both-sides XOR swizzle (T2) ----------------
// (R16 version — proven; conflicts fixed, left the top-5.)
__global__ __launch_bounds__(256) void qkv_gemm_kernel(const __bf16* __restrict__ xb,
                                                       const __bf16* __restrict__ WT,
                                                       const float* __restrict__ bq,
                                                       const float* __restrict__ bk,
                                                       const float* __restrict__ bv,
                                                       __bf16* __restrict__ qkv) {
  int which = blockIdx.z;
  const __bf16* Wt = WT + (size_t)which * DIM * DIM;
  const float* bias = (which == 0) ? bq : ((which == 1) ? bk : bv);
  __bf16* outp = qkv + (size_t)which * 2 * NH * S_LEN * HD;
  int m0 = blockIdx.y * 128;
  int n0 = blockIdx.x * 128;
  __shared__ __align__(16) char smem[36864];
  __bf16 (*As)[64] = (__bf16(*)[64])smem;            // 16384 B, linear (for global_load_lds)
  __bf16 (*Bs)[64] = (__bf16(*)[64])(smem + 16384);  // 16384 B
  __bf16 (*Ct)[136] = (__bf16(*)[136])smem;          // aliased; used only after final barrier
  int tid = threadIdx.x;
  int wave = tid >> 6, lane = tid & 63;
  int g = lane >> 4, l15 = lane & 15;
  int wm = (wave >> 1) * 64, wn = (wave & 1) * 64;
  int lr = lane >> 3;                       // 0..7 row within 8-row chunk (== LDS row & 7)
  int lc = ((lane & 7) ^ lr) * 8;           // pre-swizzled source column (elements)
  const __bf16* ga = &xb[(size_t)(m0 + wave * 32 + lr) * DIM + lc];
  const __bf16* gb = &Wt[(size_t)(n0 + wave * 32 + lr) * DIM + lc];
  int swzf = (l15 & 7) << 3;                // frag-read XOR (row&7 == l15&7 for all s)
  f32x4 acc[4][4] = {};
  for (int k0 = 0; k0 < DIM; k0 += 64) {
#pragma unroll
    for (int c = 0; c < 4; ++c) {
      GLOAD_LDS16(ga + k0 + (size_t)(c * 8) * DIM, &As[wave * 32 + c * 8][0]);
      GLOAD_LDS16(gb + k0 + (size_t)(c * 8) * DIM, &Bs[wave * 32 + c * 8][0]);
    }
    __syncthreads();
#pragma unroll
    for (int ks = 0; ks < 2; ++ks) {
      bf16x8 af[4], bfr[4];
#pragma unroll
      for (int s = 0; s < 4; ++s) {
        af[s]  = *(const bf16x8*)&As[wm + s * 16 + l15][(ks * 32 + g * 8) ^ swzf];
        bfr[s] = *(const bf16x8*)&Bs[wn + s * 16 + l15][(ks * 32 + g * 8) ^ swzf];
      }
#pragma unroll
      for (int i = 0; i < 4; ++i)
#pragma unroll
        for (int j = 0; j < 4; ++j)
          acc[i][j] = __builtin_amdgcn_mfma_f32_16x16x32_bf16(af[i], bfr[j], acc[i][j], 0, 0, 0);
    }
    __syncthreads();
  }
  if (which != 2) {
    float scale = (which == 0) ? SCALE_Q : 1.0f;
#pragma unroll
    for (int i = 0; i < 4; ++i)
#pragma unroll
      for (int j = 0; j < 4; ++j) {
        int n = n0 + wn + j * 16 + l15;
        float bval = bias[n];
#pragma unroll
        for (int r = 0; r < 4; ++r) {
          int m = m0 + wm + i * 16 + g * 4 + r;
          float val = (acc[i][j][r] + bval) * scale;
          int bb = m >> 11, ss = m & 2047;
          int hh = n >> 6, hd = n & 63;
          outp[(((size_t)bb * NH + hh) * S_LEN + ss) * HD + hd] = (__bf16)val;
        }
      }
  } else {
    // V: transpose tile in LDS (writes are bf16x4 along contiguous m), store [b,h,hd,s]
#pragma unroll
    for (int i = 0; i < 4; ++i)
#pragma unroll
      for (int j = 0; j < 4; ++j) {
        int nl = wn + j * 16 + l15;
        float bval = bias[n0 + nl];
        bf16x4 t;
#pragma unroll
        for (int r = 0; r < 4; ++r) t[r] = (__bf16)(acc[i][j][r] + bval);
        *(bf16x4*)&Ct[nl][wm + i * 16 + g * 4] = t;
      }
    __syncthreads();
#pragma unroll
    for (int it = 0; it < 8; ++it) {
      int idx = (it * 256 + tid) * 8;
      int row = idx >> 7, col = idx & 127;       // row = n_local, col = m_local
      int n = n0 + row, hh = n >> 6, hd = n & 63;
      int m = m0 + col, bb = m >> 11, ss = m & 2047;
      *(bf16x8*)&outp[(((size_t)bb * NH + hh) * HD + hd) * S_LEN + ss] =
          *(const bf16x8*)&Ct[row][col];
    }
  }
}

// ---------------- flash attention + residual, 8 waves, kt-split, dbuf, NO-MAX softmax ------
// (R19 version; c_out now stores il = 1/l directly for the mean pass.)
__global__ __launch_bounds__(512, 4) void attn_flash_kernel(const __bf16* __restrict__ qw,
                                                            const __bf16* __restrict__ kw,
                                                            const __bf16* __restrict__ vtw,
                                                            const float* __restrict__ x,
                                                            float* __restrict__ y,
                                                            float* __restrict__ c_out) {
  int h  = blockIdx.x;      // 0..15  (XCD-locality key)
  int qt = blockIdx.y;      // 0..15  (128 q-rows per block, 32 per wave)
  int b  = blockIdx.z;      // 0..1
  size_t hoff = (size_t)(b * NH + h) * S_LEN * HD;
  const __bf16* qh = qw + hoff;
  const __bf16* kh = kw + hoff;
  const __bf16* vth = vtw + hoff;     // [hd][s]
  __shared__ __align__(16) char smem[66560];
  __bf16 (*Kbase)[64] = (__bf16(*)[64])smem;            // [buf*128 + half*64 + r][64]
  __bf16 (*Vbase)[64] = (__bf16(*)[64])(smem + 32768);
  float (*ctxbuf)[64] = (float(*)[64])smem;             // [128][64] aliased, post-loop
  float* mlbuf = (float*)(smem + 65536);                // [128] l of half 1
  int tid = threadIdx.x;
  int wave = tid >> 6, lane = tid & 63;
  int half = wave >> 2, wsub = wave & 3;
  int l31 = lane & 31, hi = lane >> 5;
  int swz = (l31 & 7) << 3;
  int q = qt * 128 + wsub * 32 + l31;
  int qlocal = wsub * 32 + l31;
  // Q B-frags (col=q lane-local), direct from global, loaded once
  bf16x8 qf[4];
#pragma unroll
  for (int ks = 0; ks < 4; ++ks)
    qf[ks] = *(const bf16x8*)&qh[(size_t)q * HD + ks * 16 + hi * 8];
  // staging geometry within the 256-thread half
  int st = tid & 255;
  int sr0 = st >> 3;                  // rows 0..31 (i=0), +32 (i=1)
  int sc  = (st & 7) * 8;
  int swzs = (sr0 & 7) << 3;
  int pl = (sc & 8) ? sc - 4 : sc;    // V middle-quad permutation targets
  int ph = (sc & 8) ? sc + 4 : sc + 8;
  bf16x8 kv[2], vv[2];
  // prologue: tile 0 of this half -> buf0; issue tile 1 loads
#pragma unroll
  for (int i = 0; i < 2; ++i) {
    int r = sr0 + i * 32;
    kv[i] = *(const bf16x8*)&kh[(size_t)(half * 64 + r) * HD + sc];
    vv[i] = *(const bf16x8*)&vth[(size_t)r * S_LEN + half * 64 + sc];
  }
  {
    __bf16 (*Kd)[64] = Kbase + half * 64;
    __bf16 (*Vd)[64] = Vbase + half * 64;
#pragma unroll
    for (int i = 0; i < 2; ++i) {
      int r = sr0 + i * 32;
      *(bf16x8*)&Kd[r][sc ^ swzs] = kv[i];
      bf16x4 vlo, vhi4;
#pragma unroll
      for (int e = 0; e < 4; ++e) { vlo[e] = vv[i][e]; vhi4[e] = vv[i][e + 4]; }
      *(bf16x4*)&Vd[r][pl ^ swzs] = vlo;
      *(bf16x4*)&Vd[r][ph ^ swzs] = vhi4;
    }
  }
  {
    int ktn = 2 + half;
#pragma unroll
    for (int i = 0; i < 2; ++i) {
      int r = sr0 + i * 32;
      kv[i] = *(const bf16x8*)&kh[(size_t)(ktn * 64 + r) * HD + sc];
      vv[i] = *(const bf16x8*)&vth[(size_t)r * S_LEN + ktn * 64 + sc];
    }
  }
  float l_r = 0.f;
  f32x16 ctx0 = {}, ctx1 = {};
  __syncthreads();
  for (int t = 0; t < 16; ++t) {
    int cur = t & 1;
    const __bf16 (*Kc)[64] = (const __bf16(*)[64])(Kbase + cur * 128 + half * 64);
    const __bf16 (*Vc)[64] = (const __bf16(*)[64])(Vbase + cur * 128 + half * 64);
    // S^T[k][q]: two 32-k n-tiles
    f32x16 s0 = {}, s1 = {};
    __builtin_amdgcn_s_setprio(1);
#pragma unroll
    for (int ks = 0; ks < 4; ++ks) {
      bf16x8 k0 = *(const bf16x8*)&Kc[l31][(ks * 16 + hi * 8) ^ swz];
      bf16x8 k1 = *(const bf16x8*)&Kc[32 + l31][(ks * 16 + hi * 8) ^ swz];
      s0 = __builtin_amdgcn_mfma_f32_32x32x16_bf16(k0, qf[ks], s0, 0, 0, 0);
      s1 = __builtin_amdgcn_mfma_f32_32x32x16_bf16(k1, qf[ks], s1, 0, 0, 0);
    }
    __builtin_amdgcn_s_setprio(0);
    // P = exp2(s) (no max subtraction -- bounded logits); accumulate row-sum
    float ps = 0.f;
#pragma unroll
    for (int r = 0; r < 16; ++r) { s0[r] = __builtin_amdgcn_exp2f(s0[r]); ps += s0[r]; }
#pragma unroll
    for (int r = 0; r < 16; ++r) { s1[r] = __builtin_amdgcn_exp2f(s1[r]); ps += s1[r]; }
    ps += __shfl_xor(ps, 32);
    l_r += ps;
    // pack P -> 4 PV B-frags
    bf16x8 pa[4];
#pragma unroll
    for (int f = 0; f < 2; ++f) {
      u32x4 tt;
#pragma unroll
      for (int j = 0; j < 4; ++j) tt[j] = cvt_pk_bf16(s0[f * 8 + 2 * j], s0[f * 8 + 2 * j + 1]);
      pa[f] = __builtin_bit_cast(bf16x8, tt);
    }
#pragma unroll
    for (int f = 0; f < 2; ++f) {
      u32x4 tt;
#pragma unroll
      for (int j = 0; j < 4; ++j) tt[j] = cvt_pk_bf16(s1[f * 8 + 2 * j], s1[f * 8 + 2 * j + 1]);
      pa[2 + f] = __builtin_bit_cast(bf16x8, tt);
    }
    // O^T[hd][q] += Vperm^T x P^T
    __builtin_amdgcn_s_setprio(1);
#pragma unroll
    for (int f = 0; f < 4; ++f) {
      bf16x8 v0 = *(const bf16x8*)&Vc[l31][(f * 16 + hi * 8) ^ swz];
      bf16x8 v1 = *(const bf16x8*)&Vc[32 + l31][(f * 16 + hi * 8) ^ swz];
      ctx0 = __builtin_amdgcn_mfma_f32_32x32x16_bf16(v0, pa[f], ctx0, 0, 0, 0);
      ctx1 = __builtin_amdgcn_mfma_f32_32x32x16_bf16(v1, pa[f], ctx1, 0, 0, 0);
    }
    __builtin_amdgcn_s_setprio(0);
    // stage tile t+1 (regs, in flight for one full tile) -> buf[cur^1]; issue t+2
    if (t < 15) {
      __bf16 (*Kd)[64] = Kbase + (cur ^ 1) * 128 + half * 64;
      __bf16 (*Vd)[64] = Vbase + (cur ^ 1) * 128 + half * 64;
#pragma unroll
      for (int i = 0; i < 2; ++i) {
        int r = sr0 + i * 32;
        *(bf16x8*)&Kd[r][sc ^ swzs] = kv[i];
        bf16x4 vlo, vhi4;
#pragma unroll
        for (int e = 0; e < 4; ++e) { vlo[e] = vv[i][e]; vhi4[e] = vv[i][e + 4]; }
        *(bf16x4*)&Vd[r][pl ^ swzs] = vlo;
        *(bf16x4*)&Vd[r][ph ^ swzs] = vhi4;
      }
      if (t < 14) {
        int ktn = 2 * (t + 2) + half;
#pragma unroll
        for (int i = 0; i < 2; ++i) {
          int r = sr0 + i * 32;
          kv[i] = *(const bf16x8*)&kh[(size_t)(ktn * 64 + r) * HD + sc];
          vv[i] = *(const bf16x8*)&vth[(size_t)r * S_LEN + ktn * 64 + sc];
        }
      }
    }
    __syncthreads();
  }
  // ---- combine halves through LDS (ctxbuf aliases K buffers) ----
  int sw2 = (qlocal & 7) << 2;   // f32-unit XOR swizzle, keeps 16B alignment
  if (half == 1) {
#pragma unroll
    for (int rq = 0; rq < 4; ++rq) {
      int hd0 = rq * 8 + hi * 4;
      f32x4 a, bb;
#pragma unroll
      for (int j = 0; j < 4; ++j) { a[j] = ctx0[rq * 4 + j]; bb[j] = ctx1[rq * 4 + j]; }
      *(f32x4*)&ctxbuf[qlocal][hd0 ^ sw2] = a;
      *(f32x4*)&ctxbuf[qlocal][(32 + hd0) ^ sw2] = bb;
    }
    if (hi == 0) mlbuf[qlocal] = l_r;
  }
  __syncthreads();
  if (half == 0) {
    float l1 = mlbuf[qlocal];
    float l = l_r + l1;
    float il = 1.0f / l;
    if (lane < 32)
      c_out[(size_t)(b * NH + h) * S_LEN + qt * 128 + wsub * 32 + lane] = il;  // store 1/l
    size_t ybase = ((size_t)b * S_LEN + q) * DIM + h * HD;
#pragma unroll
    for (int rq = 0; rq < 4; ++rq) {
      int hd0 = rq * 8 + hi * 4;
      f32x4 c1 = *(const f32x4*)&ctxbuf[qlocal][hd0 ^ sw2];
      float4 xv0 = *(const float4*)&x[ybase + hd0];
      float4 o0;
      o0.x = xv0.x + (ctx0[rq * 4 + 0] + c1[0]) * il;
      o0.y = xv0.y + (ctx0[rq * 4 + 1] + c1[1]) * il;
      o0.z = xv0.z + (ctx0[rq * 4 + 2] + c1[2]) * il;
      o0.w = xv0.w + (ctx0[rq * 4 + 3] + c1[3]) * il;
      *(float4*)&y[ybase + hd0] = o0;
      int hd1 = 32 + hd0;
      f32x4 c2 = *(const f32x4*)&ctxbuf[qlocal][hd1 ^ sw2];
      float4 xv1 = *(const float4*)&x[ybase + hd1];
      float4 o1;
      o1.x = xv1.x + (ctx1[rq * 4 + 0] + c2[0]) * il;
      o1.y = xv1.y + (ctx1[rq * 4 + 1] + c2[1]) * il;
      o1.z = xv1.z + (ctx1[rq * 4 + 2] + c2[2]) * il;
      o1.w = xv1.w + (ctx1[rq * 4 + 3] + c2[3]) * il;
      *(float4*)&y[ybase + hd1] = o1;
    }
  }
}

// ---------------- head-mean, R18 skeleton, early STAGE + il-fma ----------------
// P[h][q][k] = exp2(s) * il[h][q]  (il = 1/l from flash; no subtract, bounded logits).
// Barrier + STAGE_K(h+2) hoisted to right after the MFMA block (LDS reads done there):
// the GLL gets exp2/macc(h) + all of head h+1 to land, and exp2/macc runs under it.
__global__ __launch_bounds__(256) void attn_mean_kernel(const __bf16* __restrict__ qw,
                                                        const __bf16* __restrict__ kw,
                                                        const float* __restrict__ il_in,
                                                        float* __restrict__ out_mean) {
  int kt = blockIdx.x, qt = blockIdx.y, b = blockIdx.z;
  __shared__ __align__(16) __bf16 Ks[2][64][64];
  int tid = threadIdx.x;
  int wave = tid >> 6, lane = tid & 63;
  int l31 = lane & 31, hi = lane >> 5;
  int swz = (l31 & 7) << 3;
  int q = qt * 128 + wave * 32 + l31;
  const __bf16* qp = qw + (size_t)b * NH * S_LEN * HD;
  const __bf16* kp = kw + (size_t)b * NH * S_LEN * HD;
  const float*  cp = il_in + (size_t)b * NH * S_LEN + q;
  int glr = lane >> 3;
  int glc = ((lane & 7) ^ glr) * 8;
  const __bf16* kbase = kp + (size_t)(kt * 64) * HD + glc;   // + (row)*HD + h*S_LEN*HD
#define STAGE_K(HH, BUF)                                                              \
  {                                                                                   \
    size_t hb_ = (size_t)(HH) * S_LEN * HD;                                           \
    _Pragma("unroll") for (int c_ = 0; c_ < 4; ++c_) {                                \
      int row_ = (c_ * 4 + wave) * 8 + glr;                                           \
      GLOAD_LDS16(kbase + hb_ + (size_t)row_ * HD, &Ks[BUF][(c_ * 4 + wave) * 8][0]); \
    }                                                                                 \
  }
  // prologue: K(0)->buf0, K(1)->buf1 (async; drained by first barrier)
  STAGE_K(0, 0)
  STAGE_K(1, 1)
  bf16x8 qc[4], qn[4];
#pragma unroll
  for (int ks = 0; ks < 4; ++ks) {
    qc[ks] = *(const bf16x8*)&qp[(size_t)q * HD + ks * 16 + hi * 8];
    qn[ks] = *(const bf16x8*)&qp[(size_t)S_LEN * HD + (size_t)q * HD + ks * 16 + hi * 8];
  }
  float il_c = cp[0], il_n = cp[S_LEN];
  f32x16 macc0 = {}, macc1 = {};
  __syncthreads();
  for (int h = 0; h < NH; ++h) {
    int cur = h & 1;
    f32x16 s0 = {}, s1 = {};
    __builtin_amdgcn_s_setprio(1);
#pragma unroll
    for (int ks = 0; ks < 4; ++ks) {
      bf16x8 k0 = *(const bf16x8*)&Ks[cur][l31][(ks * 16 + hi * 8) ^ swz];
      bf16x8 k1 = *(const bf16x8*)&Ks[cur][32 + l31][(ks * 16 + hi * 8) ^ swz];
      s0 = __builtin_amdgcn_mfma_f32_32x32x16_bf16(k0, qc[ks], s0, 0, 0, 0);
      s1 = __builtin_amdgcn_mfma_f32_32x32x16_bf16(k1, qc[ks], s1, 0, 0, 0);
    }
    __builtin_amdgcn_s_setprio(0);
    // all waves' Ks[cur] reads complete -> safe to restage buf[cur] for h+2.
    // GLL issued here lands during exp2/macc(h) + head h+1 (drained at h+1's barrier).
    __syncthreads();
    if (h < NH - 2) STAGE_K(h + 2, cur)
#pragma unroll
    for (int r = 0; r < 16; ++r)
      macc0[r] = fmaf(__builtin_amdgcn_exp2f(s0[r]), il_c, macc0[r]);
#pragma unroll
    for (int r = 0; r < 16; ++r)
      macc1[r] = fmaf(__builtin_amdgcn_exp2f(s1[r]), il_c, macc1[r]);
    // rotate cur/next Q and il; issue h+2 Q loads
#pragma unroll
    for (int ks = 0; ks < 4; ++ks) qc[ks] = qn[ks];
    il_c = il_n;
    if (h < NH - 2) {
      size_t hbn = (size_t)(h + 2) * S_LEN * HD;
#pragma unroll
      for (int ks = 0; ks < 4; ++ks)
        qn[ks] = *(const bf16x8*)&qp[hbn + (size_t)q * HD + ks * 16 + hi * 8];
      il_n = cp[(size_t)(h + 2) * S_LEN];
    }
  }
#undef STAGE_K
  const float invh = 1.0f / (float)NH;
  size_t obase = ((size_t)b * S_LEN + q) * S_LEN + kt * 64;
#pragma unroll
  for (int rq = 0; rq < 4; ++rq) {
    int k0i = rq * 8 + hi * 4;
    float4 o0;
    o0.x = macc0[rq * 4 + 0] * invh; o0.y = macc0[rq * 4 + 1] * invh;
    o0.z = macc0[rq * 4 + 2] * invh; o0.w = macc0[rq * 4 + 3] * invh;
    *(float4*)&out_mean[obase + k0i] = o0;
    float4 o1;
    o1.x = macc1[rq * 4 + 0] * invh; o1.y = macc1[rq * 4 + 1] * invh;
    o1.z = macc1[rq * 4 + 2] * invh; o1.w = macc1[rq * 4 + 3] * invh;
    *(float4*)&out_mean[obase + 32 + k0i] = o1;
  }
}

// ---------------- LayerNorm over D=1024 ----------------
__global__ __launch_bounds__(256) void ln_kernel(const float* __restrict__ y,
                                                 const float* __restrict__ gamma,
                                                 const float* __restrict__ beta,
                                                 float* __restrict__ out) {
  int row = blockIdx.x;
  const float* yr = y + (size_t)row * DIM;
  int tid = threadIdx.x;
  float4 v = *(const float4*)&yr[tid * 4];
  float s = v.x + v.y + v.z + v.w;
  float sq = v.x * v.x + v.y * v.y + v.z * v.z + v.w * v.w;
#pragma unroll
  for (int off = 1; off < 64; off <<= 1) {
    s += __shfl_xor(s, off);
    sq += __shfl_xor(sq, off);
  }
  __shared__ float red[8];
  int wave = tid >> 6, lane = tid & 63;
  if (lane == 0) { red[wave] = s; red[4 + wave] = sq; }
  __syncthreads();
  s = red[0] + red[1] + red[2] + red[3];
  sq = red[4] + red[5] + red[6] + red[7];
  float mu = s * (1.0f / DIM);
  float var = sq * (1.0f / DIM) - mu * mu;
  float rstd = rsqrtf(var + 1e-5f);
  float* orow = out + (size_t)row * DIM;
  float4 gv = *(const float4*)&gamma[tid * 4];
  float4 bv = *(const float4*)&beta[tid * 4];
  float4 ov;
  ov.x = (v.x - mu) * rstd * gv.x + bv.x;
  ov.y = (v.y - mu) * rstd * gv.y + bv.y;
  ov.z = (v.z - mu) * rstd * gv.z + bv.z;
  ov.w = (v.w - mu) * rstd * gv.w + bv.w;
  *(float4*)&orow[tid * 4] = ov;
}

extern "C" void kernel_launch(void* const* d_in, const int* in_sizes, int n_in,
                              void* d_out, int out_size, void* d_ws, size_t ws_size,
                              hipStream_t stream) {
  const float* x  = (const float*)d_in[0];
  const float* Wq = (const float*)d_in[1];
  const float* bq = (const float*)d_in[2];
  const float* Wk = (const float*)d_in[3];
  const float* bk = (const float*)d_in[4];
  const float* Wv = (const float*)d_in[5];
  const float* bv = (const float*)d_in[6];
  const float* gamma = (const float*)d_in[7];
  const float* beta  = (const float*)d_in[8];
  float* out = (float*)d_out;                 // [0,4194304): LN out ; [4194304,...): attn mean

  char* ws = (char*)d_ws;
  __bf16* xb   = (__bf16*)ws;                       // 8,388,608 B
  __bf16* WT   = (__bf16*)(ws + 8388608);           // 6,291,456 B
  __bf16* qkv  = (__bf16*)(ws + 14680064);          // 25,165,824 B (Q pre-scaled; V is [b,h,hd,s])
  float*  y    = (float*)(ws + 39845888);           // 16,777,216 B
  float*  c_ws = (float*)(ws + 56623104);           // 262,144 B (il = 1/l per b,h,q)

  cast_x_kernel<<<2048, 256, 0, stream>>>(x, xb);
  transW_kernel<<<dim3(16, 16, 3), 256, 0, stream>>>(Wq, Wk, Wv, WT);
  qkv_gemm_kernel<<<dim3(8, 32, 3), 256, 0, stream>>>(xb, WT, bq, bk, bv, qkv);
  attn_flash_kernel<<<dim3(16, 16, 2), 512, 0, stream>>>(qkv, qkv + 4194304, qkv + 8388608,
                                                         x, y, c_ws);
  attn_mean_kernel<<<dim3(32, 16, 2), 256, 0, stream>>>(qkv, qkv + 4194304, c_ws,
                                                        out + 4194304);
  ln_kernel<<<4096, 256, 0, stream>>>(y, gamma, beta, out);
}

// Round 21
// 159.910 us; speedup vs baseline: 1.3078x; 1.3078x over previous
//
#include <hip/hip_runtime.h>

#define S_LEN 2048
#define DIM   1024
#define NH    16
#define HD    64

typedef __bf16 bf16x8 __attribute__((ext_vector_type(8)));
typedef __bf16 bf16x4 __attribute__((ext_vector_type(4)));
typedef float  f32x4  __attribute__((ext_vector_type(4)));
typedef float  f32x16 __attribute__((ext_vector_type(16)));
typedef unsigned int u32x4 __attribute__((ext_vector_type(4)));

// softmax scale 1/8 with log2(e) folded in -> use v_exp_f32 (exp2) directly
#define SCALE_Q (0.125f * 1.44269504088896f)

#define GLOAD_LDS16(g, l) __builtin_amdgcn_global_load_lds( \
    (const __attribute__((address_space(1))) void*)(g),     \
    (__attribute__((address_space(3))) void*)(l), 16, 0, 0)

static __device__ __forceinline__ unsigned cvt_pk_bf16(float a, float b) {
  unsigned r;
  asm("v_cvt_pk_bf16_f32 %0, %1, %2" : "=v"(r) : "v"(a), "v"(b));
  return r;   // low16 = bf16(a), high16 = bf16(b)
}

// ---------------- cast x (fp32 -> bf16), 8 elems/thread ----------------
__global__ __launch_bounds__(256) void cast_x_kernel(const float* __restrict__ x,
                                                     __bf16* __restrict__ xb) {
  int i = blockIdx.x * 256 + threadIdx.x;   // 0..524287
  const float4 a = ((const float4*)x)[i * 2];
  const float4 b = ((const float4*)x)[i * 2 + 1];
  bf16x8 o;
  o[0] = (__bf16)a.x; o[1] = (__bf16)a.y; o[2] = (__bf16)a.z; o[3] = (__bf16)a.w;
  o[4] = (__bf16)b.x; o[5] = (__bf16)b.y; o[6] = (__bf16)b.z; o[7] = (__bf16)b.w;
  ((bf16x8*)xb)[i] = o;
}

// ---------------- W [k][n] fp32 -> WT [n][k] bf16, 64x64 LDS tiles ----------------
__global__ __launch_bounds__(256) void transW_kernel(const float* __restrict__ Wq,
                                                     const float* __restrict__ Wk,
                                                     const float* __restrict__ Wv,
                                                     __bf16* __restrict__ WT) {
  int which = blockIdx.z;
  const float* W = (which == 0) ? Wq : ((which == 1) ? Wk : Wv);
  __bf16* o = WT + (size_t)which * DIM * DIM;
  __shared__ __bf16 t[64][65];
  int k0 = blockIdx.y * 64, n0 = blockIdx.x * 64;
  int tid = threadIdx.x;
  int c4 = (tid & 15) * 4, rb = tid >> 4;   // rb 0..15
#pragma unroll
  for (int p = 0; p < 4; ++p) {
    int r = p * 16 + rb;
    float4 a = *(const float4*)&W[(size_t)(k0 + r) * DIM + n0 + c4];
    t[r][c4 + 0] = (__bf16)a.x; t[r][c4 + 1] = (__bf16)a.y;
    t[r][c4 + 2] = (__bf16)a.z; t[r][c4 + 3] = (__bf16)a.w;
  }
  __syncthreads();
#pragma unroll
  for (int p = 0; p < 4; ++p) {
    int n = p * 16 + rb;                     // output row (n dim)
    bf16x4 v;
    v[0] = t[c4 + 0][n]; v[1] = t[c4 + 1][n];
    v[2] = t[c4 + 2][n]; v[3] = t[c4 + 3][n];
    *(bf16x4*)&o[(size_t)(n0 + n) * DIM + k0 + c4] = v;
  }
}

// ---------------- QKV GEMM, m97 structure + both-sides XOR swizzle (T2) ----------------
__global__ __launch_bounds__(256) void qkv_gemm_kernel(const __bf16* __restrict__ xb,
                                                       const __bf16* __restrict__ WT,
                                                       const float* __restrict__ bq,
                                                       const float* __restrict__ bk,
                                                       const float* __restrict__ bv,
                                                       __bf16* __restrict__ qkv) {
  int which = blockIdx.z;
  const __bf16* Wt = WT + (size_t)which * DIM * DIM;
  const float* bias = (which == 0) ? bq : ((which == 1) ? bk : bv);
  __bf16* outp = qkv + (size_t)which * 2 * NH * S_LEN * HD;
  int m0 = blockIdx.y * 128;
  int n0 = blockIdx.x * 128;
  __shared__ __align__(16) char smem[36864];
  __bf16 (*As)[64] = (__bf16(*)[64])smem;            // 16384 B, linear (for global_load_lds)
  __bf16 (*Bs)[64] = (__bf16(*)[64])(smem + 16384);  // 16384 B
  __bf16 (*Ct)[136] = (__bf16(*)[136])smem;          // aliased; used only after final barrier
  int tid = threadIdx.x;
  int wave = tid >> 6, lane = tid & 63;
  int g = lane >> 4, l15 = lane & 15;
  int wm = (wave >> 1) * 64, wn = (wave & 1) * 64;
  int lr = lane >> 3;                       // 0..7 row within 8-row chunk (== LDS row & 7)
  int lc = ((lane & 7) ^ lr) * 8;           // pre-swizzled source column (elements)
  const __bf16* ga = &xb[(size_t)(m0 + wave * 32 + lr) * DIM + lc];
  const __bf16* gb = &Wt[(size_t)(n0 + wave * 32 + lr) * DIM + lc];
  int swzf = (l15 & 7) << 3;                // frag-read XOR (row&7 == l15&7 for all s)
  f32x4 acc[4][4] = {};
  for (int k0 = 0; k0 < DIM; k0 += 64) {
#pragma unroll
    for (int c = 0; c < 4; ++c) {
      GLOAD_LDS16(ga + k0 + (size_t)(c * 8) * DIM, &As[wave * 32 + c * 8][0]);
      GLOAD_LDS16(gb + k0 + (size_t)(c * 8) * DIM, &Bs[wave * 32 + c * 8][0]);
    }
    __syncthreads();
#pragma unroll
    for (int ks = 0; ks < 2; ++ks) {
      bf16x8 af[4], bfr[4];
#pragma unroll
      for (int s = 0; s < 4; ++s) {
        af[s]  = *(const bf16x8*)&As[wm + s * 16 + l15][(ks * 32 + g * 8) ^ swzf];
        bfr[s] = *(const bf16x8*)&Bs[wn + s * 16 + l15][(ks * 32 + g * 8) ^ swzf];
      }
#pragma unroll
      for (int i = 0; i < 4; ++i)
#pragma unroll
        for (int j = 0; j < 4; ++j)
          acc[i][j] = __builtin_amdgcn_mfma_f32_16x16x32_bf16(af[i], bfr[j], acc[i][j], 0, 0, 0);
    }
    __syncthreads();
  }
  if (which != 2) {
    float scale = (which == 0) ? SCALE_Q : 1.0f;
#pragma unroll
    for (int i = 0; i < 4; ++i)
#pragma unroll
      for (int j = 0; j < 4; ++j) {
        int n = n0 + wn + j * 16 + l15;
        float bval = bias[n];
#pragma unroll
        for (int r = 0; r < 4; ++r) {
          int m = m0 + wm + i * 16 + g * 4 + r;
          float val = (acc[i][j][r] + bval) * scale;
          int bb = m >> 11, ss = m & 2047;
          int hh = n >> 6, hd = n & 63;
          outp[(((size_t)bb * NH + hh) * S_LEN + ss) * HD + hd] = (__bf16)val;
        }
      }
  } else {
    // V: transpose tile in LDS (writes are bf16x4 along contiguous m), store [b,h,hd,s]
#pragma unroll
    for (int i = 0; i < 4; ++i)
#pragma unroll
      for (int j = 0; j < 4; ++j) {
        int nl = wn + j * 16 + l15;
        float bval = bias[n0 + nl];
        bf16x4 t;
#pragma unroll
        for (int r = 0; r < 4; ++r) t[r] = (__bf16)(acc[i][j][r] + bval);
        *(bf16x4*)&Ct[nl][wm + i * 16 + g * 4] = t;
      }
    __syncthreads();
#pragma unroll
    for (int it = 0; it < 8; ++it) {
      int idx = (it * 256 + tid) * 8;
      int row = idx >> 7, col = idx & 127;       // row = n_local, col = m_local
      int n = n0 + row, hh = n >> 6, hd = n & 63;
      int m = m0 + col, bb = m >> 11, ss = m & 2047;
      *(bf16x8*)&outp[(((size_t)bb * NH + hh) * HD + hd) * S_LEN + ss] =
          *(const bf16x8*)&Ct[row][col];
    }
  }
}

// ---------------- flash attention + residual, 8 waves, kt-split, dbuf, NO-MAX softmax ------
// h on blockIdx.x for XCD L2 locality of K/V (T1/G16); c_out = log2(l) for the mean pass.
__global__ __launch_bounds__(512, 4) void attn_flash_kernel(const __bf16* __restrict__ qw,
                                                            const __bf16* __restrict__ kw,
                                                            const __bf16* __restrict__ vtw,
                                                            const float* __restrict__ x,
                                                            float* __restrict__ y,
                                                            float* __restrict__ c_out) {
  int h  = blockIdx.x;      // 0..15  (XCD-locality key)
  int qt = blockIdx.y;      // 0..15  (128 q-rows per block, 32 per wave)
  int b  = blockIdx.z;      // 0..1
  size_t hoff = (size_t)(b * NH + h) * S_LEN * HD;
  const __bf16* qh = qw + hoff;
  const __bf16* kh = kw + hoff;
  const __bf16* vth = vtw + hoff;     // [hd][s]
  __shared__ __align__(16) char smem[66560];
  __bf16 (*Kbase)[64] = (__bf16(*)[64])smem;            // [buf*128 + half*64 + r][64]
  __bf16 (*Vbase)[64] = (__bf16(*)[64])(smem + 32768);
  float (*ctxbuf)[64] = (float(*)[64])smem;             // [128][64] aliased, post-loop
  float* mlbuf = (float*)(smem + 65536);                // [128] l of half 1
  int tid = threadIdx.x;
  int wave = tid >> 6, lane = tid & 63;
  int half = wave >> 2, wsub = wave & 3;
  int l31 = lane & 31, hi = lane >> 5;
  int swz = (l31 & 7) << 3;
  int q = qt * 128 + wsub * 32 + l31;
  int qlocal = wsub * 32 + l31;
  // Q B-frags (col=q lane-local), direct from global, loaded once
  bf16x8 qf[4];
#pragma unroll
  for (int ks = 0; ks < 4; ++ks)
    qf[ks] = *(const bf16x8*)&qh[(size_t)q * HD + ks * 16 + hi * 8];
  // staging geometry within the 256-thread half
  int st = tid & 255;
  int sr0 = st >> 3;                  // rows 0..31 (i=0), +32 (i=1)
  int sc  = (st & 7) * 8;
  int swzs = (sr0 & 7) << 3;
  int pl = (sc & 8) ? sc - 4 : sc;    // V middle-quad permutation targets
  int ph = (sc & 8) ? sc + 4 : sc + 8;
  bf16x8 kv[2], vv[2];
  // prologue: tile 0 of this half -> buf0; issue tile 1 loads
#pragma unroll
  for (int i = 0; i < 2; ++i) {
    int r = sr0 + i * 32;
    kv[i] = *(const bf16x8*)&kh[(size_t)(half * 64 + r) * HD + sc];
    vv[i] = *(const bf16x8*)&vth[(size_t)r * S_LEN + half * 64 + sc];
  }
  {
    __bf16 (*Kd)[64] = Kbase + half * 64;
    __bf16 (*Vd)[64] = Vbase + half * 64;
#pragma unroll
    for (int i = 0; i < 2; ++i) {
      int r = sr0 + i * 32;
      *(bf16x8*)&Kd[r][sc ^ swzs] = kv[i];
      bf16x4 vlo, vhi4;
#pragma unroll
      for (int e = 0; e < 4; ++e) { vlo[e] = vv[i][e]; vhi4[e] = vv[i][e + 4]; }
      *(bf16x4*)&Vd[r][pl ^ swzs] = vlo;
      *(bf16x4*)&Vd[r][ph ^ swzs] = vhi4;
    }
  }
  {
    int ktn = 2 + half;
#pragma unroll
    for (int i = 0; i < 2; ++i) {
      int r = sr0 + i * 32;
      kv[i] = *(const bf16x8*)&kh[(size_t)(ktn * 64 + r) * HD + sc];
      vv[i] = *(const bf16x8*)&vth[(size_t)r * S_LEN + ktn * 64 + sc];
    }
  }
  float l_r = 0.f;
  f32x16 ctx0 = {}, ctx1 = {};
  __syncthreads();
  for (int t = 0; t < 16; ++t) {
    int cur = t & 1;
    const __bf16 (*Kc)[64] = (const __bf16(*)[64])(Kbase + cur * 128 + half * 64);
    const __bf16 (*Vc)[64] = (const __bf16(*)[64])(Vbase + cur * 128 + half * 64);
    // S^T[k][q]: two 32-k n-tiles
    f32x16 s0 = {}, s1 = {};
    __builtin_amdgcn_s_setprio(1);
#pragma unroll
    for (int ks = 0; ks < 4; ++ks) {
      bf16x8 k0 = *(const bf16x8*)&Kc[l31][(ks * 16 + hi * 8) ^ swz];
      bf16x8 k1 = *(const bf16x8*)&Kc[32 + l31][(ks * 16 + hi * 8) ^ swz];
      s0 = __builtin_amdgcn_mfma_f32_32x32x16_bf16(k0, qf[ks], s0, 0, 0, 0);
      s1 = __builtin_amdgcn_mfma_f32_32x32x16_bf16(k1, qf[ks], s1, 0, 0, 0);
    }
    __builtin_amdgcn_s_setprio(0);
    // P = exp2(s) (no max subtraction -- bounded logits); accumulate row-sum
    float ps = 0.f;
#pragma unroll
    for (int r = 0; r < 16; ++r) { s0[r] = __builtin_amdgcn_exp2f(s0[r]); ps += s0[r]; }
#pragma unroll
    for (int r = 0; r < 16; ++r) { s1[r] = __builtin_amdgcn_exp2f(s1[r]); ps += s1[r]; }
    ps += __shfl_xor(ps, 32);
    l_r += ps;
    // pack P -> 4 PV B-frags
    bf16x8 pa[4];
#pragma unroll
    for (int f = 0; f < 2; ++f) {
      u32x4 tt;
#pragma unroll
      for (int j = 0; j < 4; ++j) tt[j] = cvt_pk_bf16(s0[f * 8 + 2 * j], s0[f * 8 + 2 * j + 1]);
      pa[f] = __builtin_bit_cast(bf16x8, tt);
    }
#pragma unroll
    for (int f = 0; f < 2; ++f) {
      u32x4 tt;
#pragma unroll
      for (int j = 0; j < 4; ++j) tt[j] = cvt_pk_bf16(s1[f * 8 + 2 * j], s1[f * 8 + 2 * j + 1]);
      pa[2 + f] = __builtin_bit_cast(bf16x8, tt);
    }
    // O^T[hd][q] += Vperm^T x P^T
    __builtin_amdgcn_s_setprio(1);
#pragma unroll
    for (int f = 0; f < 4; ++f) {
      bf16x8 v0 = *(const bf16x8*)&Vc[l31][(f * 16 + hi * 8) ^ swz];
      bf16x8 v1 = *(const bf16x8*)&Vc[32 + l31][(f * 16 + hi * 8) ^ swz];
      ctx0 = __builtin_amdgcn_mfma_f32_32x32x16_bf16(v0, pa[f], ctx0, 0, 0, 0);
      ctx1 = __builtin_amdgcn_mfma_f32_32x32x16_bf16(v1, pa[f], ctx1, 0, 0, 0);
    }
    __builtin_amdgcn_s_setprio(0);
    // stage tile t+1 (regs, in flight for one full tile) -> buf[cur^1]; issue t+2
    if (t < 15) {
      __bf16 (*Kd)[64] = Kbase + (cur ^ 1) * 128 + half * 64;
      __bf16 (*Vd)[64] = Vbase + (cur ^ 1) * 128 + half * 64;
#pragma unroll
      for (int i = 0; i < 2; ++i) {
        int r = sr0 + i * 32;
        *(bf16x8*)&Kd[r][sc ^ swzs] = kv[i];
        bf16x4 vlo, vhi4;
#pragma unroll
        for (int e = 0; e < 4; ++e) { vlo[e] = vv[i][e]; vhi4[e] = vv[i][e + 4]; }
        *(bf16x4*)&Vd[r][pl ^ swzs] = vlo;
        *(bf16x4*)&Vd[r][ph ^ swzs] = vhi4;
      }
      if (t < 14) {
        int ktn = 2 * (t + 2) + half;
#pragma unroll
        for (int i = 0; i < 2; ++i) {
          int r = sr0 + i * 32;
          kv[i] = *(const bf16x8*)&kh[(size_t)(ktn * 64 + r) * HD + sc];
          vv[i] = *(const bf16x8*)&vth[(size_t)r * S_LEN + ktn * 64 + sc];
        }
      }
    }
    __syncthreads();
  }
  // ---- combine halves through LDS (ctxbuf aliases K buffers) ----
  int sw2 = (qlocal & 7) << 2;   // f32-unit XOR swizzle, keeps 16B alignment
  if (half == 1) {
#pragma unroll
    for (int rq = 0; rq < 4; ++rq) {
      int hd0 = rq * 8 + hi * 4;
      f32x4 a, bb;
#pragma unroll
      for (int j = 0; j < 4; ++j) { a[j] = ctx0[rq * 4 + j]; bb[j] = ctx1[rq * 4 + j]; }
      *(f32x4*)&ctxbuf[qlocal][hd0 ^ sw2] = a;
      *(f32x4*)&ctxbuf[qlocal][(32 + hd0) ^ sw2] = bb;
    }
    if (hi == 0) mlbuf[qlocal] = l_r;
  }
  __syncthreads();
  if (half == 0) {
    float l1 = mlbuf[qlocal];
    float l = l_r + l1;
    float il = 1.0f / l;
    float cvl = __builtin_amdgcn_logf(l);   // c = log2(l), exp2-domain (m == 0)
    if (lane < 32)
      c_out[(size_t)(b * NH + h) * S_LEN + qt * 128 + wsub * 32 + lane] = cvl;
    size_t ybase = ((size_t)b * S_LEN + q) * DIM + h * HD;
#pragma unroll
    for (int rq = 0; rq < 4; ++rq) {
      int hd0 = rq * 8 + hi * 4;
      f32x4 c1 = *(const f32x4*)&ctxbuf[qlocal][hd0 ^ sw2];
      float4 xv0 = *(const float4*)&x[ybase + hd0];
      float4 o0;
      o0.x = xv0.x + (ctx0[rq * 4 + 0] + c1[0]) * il;
      o0.y = xv0.y + (ctx0[rq * 4 + 1] + c1[1]) * il;
      o0.z = xv0.z + (ctx0[rq * 4 + 2] + c1[2]) * il;
      o0.w = xv0.w + (ctx0[rq * 4 + 3] + c1[3]) * il;
      *(float4*)&y[ybase + hd0] = o0;
      int hd1 = 32 + hd0;
      f32x4 c2 = *(const f32x4*)&ctxbuf[qlocal][hd1 ^ sw2];
      float4 xv1 = *(const float4*)&x[ybase + hd1];
      float4 o1;
      o1.x = xv1.x + (ctx1[rq * 4 + 0] + c2[0]) * il;
      o1.y = xv1.y + (ctx1[rq * 4 + 1] + c2[1]) * il;
      o1.z = xv1.z + (ctx1[rq * 4 + 2] + c2[2]) * il;
      o1.w = xv1.w + (ctx1[rq * 4 + 3] + c2[3]) * il;
      *(float4*)&y[ybase + hd1] = o1;
    }
  }
}

// ---------------- head-mean, R18 skeleton + global_load_lds K staging ----------------
// (exact R18/R19 version — proven 55.8 µs; STAGE_K at end of iteration, c subtract.)
__global__ __launch_bounds__(256) void attn_mean_kernel(const __bf16* __restrict__ qw,
                                                        const __bf16* __restrict__ kw,
                                                        const float* __restrict__ c_in,
                                                        float* __restrict__ out_mean) {
  int kt = blockIdx.x, qt = blockIdx.y, b = blockIdx.z;
  __shared__ __align__(16) __bf16 Ks[2][64][64];
  int tid = threadIdx.x;
  int wave = tid >> 6, lane = tid & 63;
  int l31 = lane & 31, hi = lane >> 5;
  int swz = (l31 & 7) << 3;
  int q = qt * 128 + wave * 32 + l31;
  const __bf16* qp = qw + (size_t)b * NH * S_LEN * HD;
  const __bf16* kp = kw + (size_t)b * NH * S_LEN * HD;
  const float*  cp = c_in + (size_t)b * NH * S_LEN + q;
  int glr = lane >> 3;
  int glc = ((lane & 7) ^ glr) * 8;
  const __bf16* kbase = kp + (size_t)(kt * 64) * HD + glc;   // + (row)*HD + h*S_LEN*HD
#define STAGE_K(HH, BUF)                                                              \
  {                                                                                   \
    size_t hb_ = (size_t)(HH) * S_LEN * HD;                                           \
    _Pragma("unroll") for (int c_ = 0; c_ < 4; ++c_) {                                \
      int row_ = (c_ * 4 + wave) * 8 + glr;                                           \
      GLOAD_LDS16(kbase + hb_ + (size_t)row_ * HD, &Ks[BUF][(c_ * 4 + wave) * 8][0]); \
    }                                                                                 \
  }
  // prologue: K(0)->buf0, K(1)->buf1 (async; drained by first barrier)
  STAGE_K(0, 0)
  STAGE_K(1, 1)
  bf16x8 qc[4], qn[4];
#pragma unroll
  for (int ks = 0; ks < 4; ++ks) {
    qc[ks] = *(const bf16x8*)&qp[(size_t)q * HD + ks * 16 + hi * 8];
    qn[ks] = *(const bf16x8*)&qp[(size_t)S_LEN * HD + (size_t)q * HD + ks * 16 + hi * 8];
  }
  float c_c = cp[0], c_n = cp[S_LEN];
  f32x16 macc0 = {}, macc1 = {};
  __syncthreads();
  for (int h = 0; h < NH; ++h) {
    int cur = h & 1;
    f32x16 s0 = {}, s1 = {};
    __builtin_amdgcn_s_setprio(1);
#pragma unroll
    for (int ks = 0; ks < 4; ++ks) {
      bf16x8 k0 = *(const bf16x8*)&Ks[cur][l31][(ks * 16 + hi * 8) ^ swz];
      bf16x8 k1 = *(const bf16x8*)&Ks[cur][32 + l31][(ks * 16 + hi * 8) ^ swz];
      s0 = __builtin_amdgcn_mfma_f32_32x32x16_bf16(k0, qc[ks], s0, 0, 0, 0);
      s1 = __builtin_amdgcn_mfma_f32_32x32x16_bf16(k1, qc[ks], s1, 0, 0, 0);
    }
    __builtin_amdgcn_s_setprio(0);
#pragma unroll
    for (int r = 0; r < 16; ++r) macc0[r] += __builtin_amdgcn_exp2f(s0[r] - c_c);
#pragma unroll
    for (int r = 0; r < 16; ++r) macc1[r] += __builtin_amdgcn_exp2f(s1[r] - c_c);
    // rotate cur/next Q and c; issue h+2 Q loads
#pragma unroll
    for (int ks = 0; ks < 4; ++ks) qc[ks] = qn[ks];
    c_c = c_n;
    if (h < NH - 2) {
      size_t hbn = (size_t)(h + 2) * S_LEN * HD;
#pragma unroll
      for (int ks = 0; ks < 4; ++ks)
        qn[ks] = *(const bf16x8*)&qp[hbn + (size_t)q * HD + ks * 16 + hi * 8];
      c_n = cp[(size_t)(h + 2) * S_LEN];
    }
    __syncthreads();                 // all waves done reading Ks[cur]
    if (h < NH - 2) STAGE_K(h + 2, cur)   // lands during head h+1's compute
  }
#undef STAGE_K
  const float invh = 1.0f / (float)NH;
  size_t obase = ((size_t)b * S_LEN + q) * S_LEN + kt * 64;
#pragma unroll
  for (int rq = 0; rq < 4; ++rq) {
    int k0i = rq * 8 + hi * 4;
    float4 o0;
    o0.x = macc0[rq * 4 + 0] * invh; o0.y = macc0[rq * 4 + 1] * invh;
    o0.z = macc0[rq * 4 + 2] * invh; o0.w = macc0[rq * 4 + 3] * invh;
    *(float4*)&out_mean[obase + k0i] = o0;
    float4 o1;
    o1.x = macc1[rq * 4 + 0] * invh; o1.y = macc1[rq * 4 + 1] * invh;
    o1.z = macc1[rq * 4 + 2] * invh; o1.w = macc1[rq * 4 + 3] * invh;
    *(float4*)&out_mean[obase + 32 + k0i] = o1;
  }
}

// ---------------- LayerNorm over D=1024 ----------------
__global__ __launch_bounds__(256) void ln_kernel(const float* __restrict__ y,
                                                 const float* __restrict__ gamma,
                                                 const float* __restrict__ beta,
                                                 float* __restrict__ out) {
  int row = blockIdx.x;
  const float* yr = y + (size_t)row * DIM;
  int tid = threadIdx.x;
  float4 v = *(const float4*)&yr[tid * 4];
  float s = v.x + v.y + v.z + v.w;
  float sq = v.x * v.x + v.y * v.y + v.z * v.z + v.w * v.w;
#pragma unroll
  for (int off = 1; off < 64; off <<= 1) {
    s += __shfl_xor(s, off);
    sq += __shfl_xor(sq, off);
  }
  __shared__ float red[8];
  int wave = tid >> 6, lane = tid & 63;
  if (lane == 0) { red[wave] = s; red[4 + wave] = sq; }
  __syncthreads();
  s = red[0] + red[1] + red[2] + red[3];
  sq = red[4] + red[5] + red[6] + red[7];
  float mu = s * (1.0f / DIM);
  float var = sq * (1.0f / DIM) - mu * mu;
  float rstd = rsqrtf(var + 1e-5f);
  float* orow = out + (size_t)row * DIM;
  float4 gv = *(const float4*)&gamma[tid * 4];
  float4 bv = *(const float4*)&beta[tid * 4];
  float4 ov;
  ov.x = (v.x - mu) * rstd * gv.x + bv.x;
  ov.y = (v.y - mu) * rstd * gv.y + bv.y;
  ov.z = (v.z - mu) * rstd * gv.z + bv.z;
  ov.w = (v.w - mu) * rstd * gv.w + bv.w;
  *(float4*)&orow[tid * 4] = ov;
}

extern "C" void kernel_launch(void* const* d_in, const int* in_sizes, int n_in,
                              void* d_out, int out_size, void* d_ws, size_t ws_size,
                              hipStream_t stream) {
  const float* x  = (const float*)d_in[0];
  const float* Wq = (const float*)d_in[1];
  const float* bq = (const float*)d_in[2];
  const float* Wk = (const float*)d_in[3];
  const float* bk = (const float*)d_in[4];
  const float* Wv = (const float*)d_in[5];
  const float* bv = (const float*)d_in[6];
  const float* gamma = (const float*)d_in[7];
  const float* beta  = (const float*)d_in[8];
  float* out = (float*)d_out;                 // [0,4194304): LN out ; [4194304,...): attn mean

  char* ws = (char*)d_ws;
  __bf16* xb   = (__bf16*)ws;                       // 8,388,608 B
  __bf16* WT   = (__bf16*)(ws + 8388608);           // 6,291,456 B
  __bf16* qkv  = (__bf16*)(ws + 14680064);          // 25,165,824 B (Q pre-scaled; V is [b,h,hd,s])
  float*  y    = (float*)(ws + 39845888);           // 16,777,216 B
  float*  c_ws = (float*)(ws + 56623104);           // 262,144 B (log2(l) per b,h,q)

  cast_x_kernel<<<2048, 256, 0, stream>>>(x, xb);
  transW_kernel<<<dim3(16, 16, 3), 256, 0, stream>>>(Wq, Wk, Wv, WT);
  qkv_gemm_kernel<<<dim3(8, 32, 3), 256, 0, stream>>>(xb, WT, bq, bk, bv, qkv);
  attn_flash_kernel<<<dim3(16, 16, 2), 512, 0, stream>>>(qkv, qkv + 4194304, qkv + 8388608,
                                                         x, y, c_ws);
  attn_mean_kernel<<<dim3(32, 16, 2), 256, 0, stream>>>(qkv, qkv + 4194304, c_ws,
                                                        out + 4194304);
  ln_kernel<<<4096, 256, 0, stream>>>(y, gamma, beta, out);
}